// Round 11
// baseline (594.004 us; speedup 1.0000x reference)
//
#include <hip/hip_runtime.h>

typedef unsigned short u16;

#define NT   16384
#define LAYERS 6

using bf16x8 = __attribute__((ext_vector_type(8))) __bf16;
using f32x4  = __attribute__((ext_vector_type(4))) float;

#define MFMA __builtin_amdgcn_mfma_f32_16x16x32_bf16

__device__ __forceinline__ u16 f2bf(float x){
  unsigned u = __float_as_uint(x);
  u += 0x7fffu + ((u >> 16) & 1u);
  return (u16)(u >> 16);
}
__device__ __forceinline__ float bf2f(u16 u){
  return __uint_as_float(((unsigned)u) << 16);
}

__device__ __forceinline__ void gll16(const u16* g, u16* l){
  __builtin_amdgcn_global_load_lds(
      (const __attribute__((address_space(1))) unsigned int*)g,
      (__attribute__((address_space(3))) unsigned int*)l, 16, 0, 0);
}

// ---------------------------------------------------------------------------
// Weight transpose+convert: fp32 [K=256][N] -> bf16 [Npad][256] (row n = W[:,n])
// ---------------------------------------------------------------------------
__global__ __launch_bounds__(256) void wconv_k(
    const float* __restrict__ Wq, const float* __restrict__ Wk,
    const float* __restrict__ Wv, const float* __restrict__ Wo,
    const float* __restrict__ W1, const float* __restrict__ W2,
    const float* __restrict__ Wlm, u16* __restrict__ WT)
{
  __shared__ float tile[64][65];
  const int z = blockIdx.z;
  const float* src; u16* dst; int N = 256, Npad = 256;
  if (z < 18){
    const int l = z / 3, which = z % 3;
    const float* a[3] = {Wq, Wk, Wv};
    src = a[which] + (size_t)l * 65536;
    dst = WT + (size_t)l * 196608 + (size_t)which * 65536;
  } else if (z < 36){
    const int i = z - 18, j = i / 6, l = i % 6;
    const float* a[3] = {Wo, W1, W2};
    src = a[j] + (size_t)l * 65536;
    dst = WT + 1179648 + (size_t)(j * 6 + l) * 65536;
  } else {
    src = Wlm; dst = WT + 2359296; N = 96; Npad = 128;
  }
  const int n0 = blockIdx.y * 64, k0 = blockIdx.x * 64;
  if (n0 >= Npad) return;
  const int c = threadIdx.x & 63, r0 = threadIdx.x >> 6;
  #pragma unroll
  for (int i = 0; i < 16; ++i){
    const int r = r0 + i * 4;
    tile[r][c] = (n0 + c < N) ? src[(size_t)(k0 + r) * N + n0 + c] : 0.f;
  }
  __syncthreads();
  #pragma unroll
  for (int i = 0; i < 16; ++i){
    const int cp = r0 + i * 4;
    dst[(size_t)(n0 + cp) * 256 + k0 + c] = f2bf(tile[c][cp]);
  }
}

// ---------------------------------------------------------------------------
// Embedding: wave per row -> X bf16.
// ---------------------------------------------------------------------------
__global__ __launch_bounds__(256) void embed_k(
    const int* __restrict__ idx, const float* __restrict__ tok,
    const float* __restrict__ pos, u16* __restrict__ X)
{
  const int w = threadIdx.x >> 6, l = threadIdx.x & 63;
  const int r = blockIdx.x * 4 + w;
  const int id = idx[r];
  float4 tv = *reinterpret_cast<const float4*>(tok + (size_t)id * 256 + l * 4);
  float4 pv = *reinterpret_cast<const float4*>(pos + (size_t)(r & 255) * 256 + l * 4);
  union { u16 u[4]; uint2 q; } p;
  p.u[0] = f2bf(tv.x + pv.x); p.u[1] = f2bf(tv.y + pv.y);
  p.u[2] = f2bf(tv.z + pv.z); p.u[3] = f2bf(tv.w + pv.w);
  *reinterpret_cast<uint2*>(X + (size_t)r * 256 + l * 4) = p.q;
}

// ---------------------------------------------------------------------------
// GEMM v3 (layer-0 QKV only): both operands LDS-staged, double-buffered.
// ---------------------------------------------------------------------------
template<int TM, int TN, int THREADS, int WR, int WC>
__global__ __launch_bounds__(THREADS) void gemm3_k(
    const u16* __restrict__ A, const u16* __restrict__ WT,
    u16* __restrict__ outp, int ldo)
{
  constexpr int MR = TM / (WR * 16), NR = TN / (WC * 16);
  extern __shared__ char smem[];
  u16* As = (u16*)smem;
  u16* Bs = As + 2 * TM * 64;

  const int t = threadIdx.x, l = t & 63, w = t >> 6;
  const int wr = w / WC, wc = w % WC;
  const int m0 = blockIdx.x * TM, n0 = blockIdx.y * TN;
  const int lr = l & 15, lk = (l >> 4) * 8, rj = (l >> 4) * 4;
  const int rb = wr * (TM / WR), cb = wc * (TN / WC);
  f32x4 acc[MR][NR] = {};

  auto stage = [&](int buf, int kt){
    const int k0 = kt * 64;
    u16* as = As + buf * (TM * 64);
    u16* bs = Bs + buf * (TN * 64);
    #pragma unroll
    for (int ci = t; ci < TM * 8; ci += THREADS){
      const int eo = ci * 8;
      gll16(A + (size_t)(m0 + (eo >> 6)) * 256 + k0 + (eo & 63), as + eo);
    }
    #pragma unroll
    for (int ci = t; ci < TN * 8; ci += THREADS){
      const int eo = ci * 8;
      gll16(WT + (size_t)(n0 + (eo >> 6)) * 256 + k0 + (eo & 63), bs + eo);
    }
  };
  auto compute = [&](int buf){
    const u16* as = As + buf * (TM * 64);
    const u16* bs = Bs + buf * (TN * 64);
    #pragma unroll
    for (int kk = 0; kk < 64; kk += 32){
      bf16x8 af[MR], bfv[NR];
      #pragma unroll
      for (int m = 0; m < MR; ++m)
        af[m] = *reinterpret_cast<const bf16x8*>(&as[(rb + m*16 + lr) * 64 + kk + lk]);
      #pragma unroll
      for (int n = 0; n < NR; ++n)
        bfv[n] = *reinterpret_cast<const bf16x8*>(&bs[(cb + n*16 + lr) * 64 + kk + lk]);
      #pragma unroll
      for (int m = 0; m < MR; ++m)
        #pragma unroll
        for (int n = 0; n < NR; ++n)
          acc[m][n] = MFMA(af[m], bfv[n], acc[m][n], 0, 0, 0);
    }
  };

  stage(0, 0);
  __syncthreads();
  #pragma unroll
  for (int kt = 0; kt < 4; ++kt){
    if (kt < 3) stage((kt + 1) & 1, kt + 1);
    compute(kt & 1);
    if (kt < 3) __syncthreads();
  }
  #pragma unroll
  for (int m = 0; m < MR; ++m)
    #pragma unroll
    for (int n = 0; n < NR; ++n){
      const int gcol = n0 + cb + n*16 + lr;
      #pragma unroll
      for (int j = 0; j < 4; ++j){
        const int grow = m0 + rb + m*16 + rj + j;
        outp[(size_t)grow * ldo + gcol] = f2bf(acc[m][n][j]);
      }
    }
}

// ---------------------------------------------------------------------------
// Fused layer-tail kernel (unchanged from r10).
// ---------------------------------------------------------------------------
template<int TN2, int NCH, bool RELU2, bool BIAS2, bool LNF, bool F32O2>
__global__ __launch_bounds__(1024) void gemmF_k(
    const u16* __restrict__ A, const u16* __restrict__ Bw1,
    const float* __restrict__ bias1, u16* __restrict__ X,
    const float* __restrict__ lnw, const float* __restrict__ lnb,
    const u16* __restrict__ Bw2, const float* __restrict__ bias2,
    void* __restrict__ out2, int ldo2,
    const float* __restrict__ lnfw, const float* __restrict__ lnfb)
{
  constexpr int NR2 = TN2 / 128;
  extern __shared__ char smem[];
  u16* As = (u16*)smem;          // [2][64*64]
  u16* Bs = As + 8192;           // [2][256*64]
  u16* Xn = Bs + 32768;          // [64][264]
  float* redS = (float*)(Xn + 16896);
  float* redQ = redS + 64 * 9;

  const int t = threadIdx.x, l = t & 63, w = t >> 6;
  const int wr = w >> 3, wc = w & 7;
  const int m0 = blockIdx.x * 64;
  const int lr = l & 15, lk = (l >> 4) * 8, rj = (l >> 4) * 4;
  const int rb = wr * 32, cb = wc * 32;
  const int cb2 = wc * (TN2 / 8);

  auto stage1 = [&](int buf, int kt){
    const int k0 = kt * 64;
    u16* as = As + buf * 4096;
    u16* bs = Bs + buf * 16384;
    if (t < 512){
      const int eo = t * 8;
      gll16(A + (size_t)(m0 + (eo >> 6)) * 256 + k0 + (eo & 63), as + eo);
    }
    #pragma unroll
    for (int i = 0; i < 2; ++i){
      const int eo = (i * 1024 + t) * 8;
      gll16(Bw1 + (size_t)(eo >> 6) * 256 + k0 + (eo & 63), bs + eo);
    }
  };
  auto stage2 = [&](int buf, int nc, int kt){
    const int k0 = kt * 64;
    u16* bs = Bs + buf * 16384;
    #pragma unroll
    for (int i = 0; i < TN2 / 128; ++i){
      const int eo = (i * 1024 + t) * 8;
      gll16(Bw2 + (size_t)(nc * TN2 + (eo >> 6)) * 256 + k0 + (eo & 63), bs + eo);
    }
  };

  // ---- phase 1 ----
  f32x4 acc[2][2] = {};
  stage1(0, 0);
  __syncthreads();
  #pragma unroll
  for (int kt = 0; kt < 4; ++kt){
    if (kt < 3) stage1((kt + 1) & 1, kt + 1);
    const u16* as = As + (kt & 1) * 4096;
    const u16* bs = Bs + (kt & 1) * 16384;
    #pragma unroll
    for (int kk = 0; kk < 64; kk += 32){
      bf16x8 af[2], bfv[2];
      #pragma unroll
      for (int m = 0; m < 2; ++m)
        af[m] = *reinterpret_cast<const bf16x8*>(&as[(rb + m*16 + lr) * 64 + kk + lk]);
      #pragma unroll
      for (int n = 0; n < 2; ++n)
        bfv[n] = *reinterpret_cast<const bf16x8*>(&bs[(cb + n*16 + lr) * 64 + kk + lk]);
      #pragma unroll
      for (int m = 0; m < 2; ++m)
        #pragma unroll
        for (int n = 0; n < 2; ++n)
          acc[m][n] = MFMA(af[m], bfv[n], acc[m][n], 0, 0, 0);
    }
    if (kt < 3) __syncthreads();
  }

  stage2(0, 0, 0);

  #pragma unroll
  for (int m = 0; m < 2; ++m){
    #pragma unroll
    for (int j = 0; j < 4; ++j){
      const int lrow = rb + m*16 + rj + j;
      float s = 0.f, q = 0.f;
      #pragma unroll
      for (int n = 0; n < 2; ++n){
        const int col = cb + n*16 + lr;
        float v = acc[m][n][j] + bias1[col] + bf2f(X[(size_t)(m0 + lrow) * 256 + col]);
        acc[m][n][j] = v;
        s += v; q += v * v;
      }
      #pragma unroll
      for (int o = 1; o < 16; o <<= 1){ s += __shfl_xor(s, o); q += __shfl_xor(q, o); }
      if (lr == 0){ redS[lrow*9 + wc] = s; redQ[lrow*9 + wc] = q; }
    }
  }
  __syncthreads();
  #pragma unroll
  for (int m = 0; m < 2; ++m){
    #pragma unroll
    for (int j = 0; j < 4; ++j){
      const int lrow = rb + m*16 + rj + j;
      float s = 0.f, q = 0.f;
      #pragma unroll
      for (int c = 0; c < 8; ++c){ s += redS[lrow*9 + c]; q += redQ[lrow*9 + c]; }
      const float mean = s * (1.f/256.f);
      const float rstd = rsqrtf(q * (1.f/256.f) - mean*mean + 1e-5f);
      #pragma unroll
      for (int n = 0; n < 2; ++n){
        const int col = cb + n*16 + lr;
        const u16 y = f2bf((acc[m][n][j] - mean) * rstd * lnw[col] + lnb[col]);
        Xn[lrow*264 + col] = y;
        X[(size_t)(m0 + lrow) * 256 + col] = y;
      }
    }
  }

  if constexpr (LNF){
    __syncthreads();
    #pragma unroll
    for (int rr = 0; rr < 4; ++rr){
      const int row = w * 4 + rr;
      union { uint2 q2; u16 u[4]; } iv;
      iv.q2 = *reinterpret_cast<const uint2*>(Xn + row*264 + l*4);
      float v0 = bf2f(iv.u[0]), v1 = bf2f(iv.u[1]), v2 = bf2f(iv.u[2]), v3 = bf2f(iv.u[3]);
      float s = v0 + v1 + v2 + v3;
      float q = v0*v0 + v1*v1 + v2*v2 + v3*v3;
      #pragma unroll
      for (int o = 1; o < 64; o <<= 1){ s += __shfl_xor(s, o); q += __shfl_xor(q, o); }
      const float mean = s * (1.f/256.f);
      const float rstd = rsqrtf(q * (1.f/256.f) - mean*mean + 1e-5f);
      union { u16 u[4]; uint2 q2; } p;
      p.u[0] = f2bf((v0 - mean) * rstd * lnfw[l*4+0] + lnfb[l*4+0]);
      p.u[1] = f2bf((v1 - mean) * rstd * lnfw[l*4+1] + lnfb[l*4+1]);
      p.u[2] = f2bf((v2 - mean) * rstd * lnfw[l*4+2] + lnfb[l*4+2]);
      p.u[3] = f2bf((v3 - mean) * rstd * lnfw[l*4+3] + lnfb[l*4+3]);
      *reinterpret_cast<uint2*>(Xn + row*264 + l*4) = p.q2;
    }
  }
  __syncthreads();

  // ---- phase 2 ----
  #pragma unroll 1
  for (int nc = 0; nc < NCH; ++nc){
    f32x4 a2[2][NR2] = {};
    #pragma unroll
    for (int kt = 0; kt < 4; ++kt){
      const int s = nc*4 + kt, nx = s + 1;
      if (nx < NCH*4) stage2(nx & 1, nx >> 2, nx & 3);
      const u16* bs = Bs + (s & 1) * 16384;
      #pragma unroll
      for (int kk2 = 0; kk2 < 64; kk2 += 32){
        const int kk = kt*64 + kk2;
        bf16x8 af[2], bfv[NR2];
        #pragma unroll
        for (int m = 0; m < 2; ++m)
          af[m] = *reinterpret_cast<const bf16x8*>(Xn + (rb + m*16 + lr)*264 + kk + lk);
        #pragma unroll
        for (int n = 0; n < NR2; ++n)
          bfv[n] = *reinterpret_cast<const bf16x8*>(&bs[(cb2 + n*16 + lr)*64 + kk2 + lk]);
        #pragma unroll
        for (int m = 0; m < 2; ++m)
          #pragma unroll
          for (int n = 0; n < NR2; ++n)
            a2[m][n] = MFMA(af[m], bfv[n], a2[m][n], 0, 0, 0);
      }
      if (nx < NCH*4) __syncthreads();
    }
    #pragma unroll
    for (int m = 0; m < 2; ++m){
      #pragma unroll
      for (int n = 0; n < NR2; ++n){
        const int col = nc*TN2 + cb2 + n*16 + lr;
        #pragma unroll
        for (int j = 0; j < 4; ++j){
          const int grow = m0 + rb + m*16 + rj + j;
          float v = a2[m][n][j];
          if (BIAS2) v += bias2[col];
          if (RELU2) v = fmaxf(v, 0.f);
          if (F32O2){
            if (col < 96) ((float*)out2)[(size_t)grow * ldo2 + col] = v;
          } else {
            ((u16*)out2)[(size_t)grow * ldo2 + col] = f2bf(v);
          }
        }
      }
    }
  }
}

// ---------------------------------------------------------------------------
// Attention v3: block per (b,h), 256 thr. TWO barriers total.
// Stage K [256][40] + V^T [32][264]; kf -> regs; Ps [64][268] ALIASES Ks
// (dead after kf). P rows are wave-private => chunk loop needs no barriers
// (same-wave ds ordering via lgkmcnt). Q frags direct from global (1/wave/chunk).
// LDS 51200 B -> 3 blocks/CU.
// ---------------------------------------------------------------------------
__global__ __launch_bounds__(256) void attn3_k(
    const u16* __restrict__ QKV, u16* __restrict__ O)
{
  extern __shared__ char smem[];
  u16* Ks = (u16*)smem;                 // [256][40] phase A
  u16* Ps = (u16*)smem;                 // [64][268] phase B (aliases Ks)
  u16* VT = (u16*)smem + 64 * 268;      // [32][264]

  const int bh = blockIdx.x, b = bh >> 3, h = bh & 7;
  const size_t rbase = (size_t)b * 256 * 768;
  const int qc = h * 32, kc = 256 + h * 32, vc = 512 + h * 32;
  const int t = threadIdx.x, l = t & 63, w = t >> 6;
  const int lr = l & 15, lk = (l >> 4) * 8, rj = (l >> 4) * 4;
  const int r4 = t >> 2, c8 = (t & 3) * 8;

  #pragma unroll
  for (int it = 0; it < 4; ++it){
    const int row = it * 64 + r4;
    *reinterpret_cast<uint4*>(Ks + row * 40 + c8) =
        *reinterpret_cast<const uint4*>(QKV + rbase + (size_t)row * 768 + kc + c8);
    union { uint4 q; u16 u[8]; } p;
    p.q = *reinterpret_cast<const uint4*>(QKV + rbase + (size_t)row * 768 + vc + c8);
    #pragma unroll
    for (int j2 = 0; j2 < 8; ++j2) VT[(c8 + j2) * 264 + row] = p.u[j2];
  }
  __syncthreads();

  bf16x8 kf[16];
  #pragma unroll
  for (int n = 0; n < 16; ++n)
    kf[n] = *reinterpret_cast<const bf16x8*>(Ks + (n*16 + lr) * 40 + lk);
  __syncthreads();   // all kf in regs; Ps may now overwrite Ks

  #pragma unroll 1
  for (int c = 0; c < 4; ++c){
    const int rowq = c * 64 + w * 16;
    bf16x8 qa = *reinterpret_cast<const bf16x8*>(
        QKV + rbase + (size_t)(rowq + lr) * 768 + qc + lk);
    const int nmax = 4 * (c + 1);
    f32x4 s[16];
    #pragma unroll
    for (int n = 0; n < 16; ++n){
      if (n < nmax){ f32x4 z = {}; s[n] = MFMA(qa, kf[n], z, 0, 0, 0); }
    }
    float inv[4];
    #pragma unroll
    for (int j = 0; j < 4; ++j){
      const int tq = rowq + rj + j;
      float m = -1e30f;
      #pragma unroll
      for (int n = 0; n < 16; ++n){
        if (n < nmax){
          float v = s[n][j] * 0.0625f;
          v = ((n*16 + lr) <= tq) ? v : -1e30f;
          s[n][j] = v;
          m = fmaxf(m, v);
        }
      }
      #pragma unroll
      for (int o = 1; o < 16; o <<= 1) m = fmaxf(m, __shfl_xor(m, o));
      float sum = 0.f;
      #pragma unroll
      for (int n = 0; n < 16; ++n){
        if (n < nmax){
          const float p = __expf(s[n][j] - m);
          sum += p;
          Ps[(w*16 + rj + j) * 268 + n*16 + lr] = f2bf(p);
        }
      }
      #pragma unroll
      for (int o = 1; o < 16; o <<= 1) sum += __shfl_xor(sum, o);
      inv[j] = 1.f / sum;
    }

    f32x4 o0 = {}, o1 = {};
    #pragma unroll
    for (int k2 = 0; k2 < 8; ++k2){
      if (k2 < 2 * (c + 1)){
        bf16x8 pa  = *reinterpret_cast<const bf16x8*>(Ps + (w*16 + lr) * 268 + k2*32 + lk);
        bf16x8 vb0 = *reinterpret_cast<const bf16x8*>(VT + lr * 264 + k2*32 + lk);
        bf16x8 vb1 = *reinterpret_cast<const bf16x8*>(VT + (16 + lr) * 264 + k2*32 + lk);
        o0 = MFMA(pa, vb0, o0, 0, 0, 0);
        o1 = MFMA(pa, vb1, o1, 0, 0, 0);
      }
    }
    #pragma unroll
    for (int j = 0; j < 4; ++j){
      const int row = rowq + rj + j;
      u16* op = O + (size_t)(b*256 + row) * 256 + h*32;
      op[lr]      = f2bf(o0[j] * inv[j]);
      op[16 + lr] = f2bf(o1[j] * inv[j]);
    }
  }
}

// ---------------------------------------------------------------------------
// NLL + loss
// ---------------------------------------------------------------------------
__global__ __launch_bounds__(256) void nll_k(
    const float* __restrict__ logits, const int* __restrict__ target,
    float* __restrict__ nll)
{
  const int w = threadIdx.x >> 6, l = threadIdx.x & 63;
  const int r = blockIdx.x * 4 + w;
  const float* row = logits + (size_t)r * 96;
  float v0 = row[l];
  float v1 = (l < 32) ? row[64 + l] : -1e30f;
  float m = fmaxf(v0, v1);
  #pragma unroll
  for (int o = 32; o; o >>= 1) m = fmaxf(m, __shfl_xor(m, o));
  float s = __expf(v0 - m) + ((l < 32) ? __expf(v1 - m) : 0.f);
  #pragma unroll
  for (int o = 32; o; o >>= 1) s += __shfl_xor(s, o);
  if (l == 0) nll[r] = logf(s) + m - row[target[r]];
}

__global__ __launch_bounds__(256) void loss_k(
    const float* __restrict__ nll, float* __restrict__ out)
{
  __shared__ float rs[4];
  float s = 0.f;
  for (int i = threadIdx.x; i < NT; i += 256) s += nll[i];
  #pragma unroll
  for (int o = 32; o; o >>= 1) s += __shfl_xor(s, o);
  if ((threadIdx.x & 63) == 0) rs[threadIdx.x >> 6] = s;
  __syncthreads();
  if (threadIdx.x == 0) out[0] = (rs[0] + rs[1] + rs[2] + rs[3]) * (1.f / 16384.f);
}

// ---------------------------------------------------------------------------
extern "C" void kernel_launch(void* const* d_in, const int* in_sizes, int n_in,
                              void* d_out, int out_size, void* d_ws, size_t ws_size,
                              hipStream_t stream)
{
  const int*   idx    = (const int*)  d_in[0];
  const int*   target = (const int*)  d_in[1];
  const float* tok    = (const float*)d_in[2];
  const float* pos    = (const float*)d_in[3];
  const float* bo     = (const float*)d_in[8];
  const float* b1     = (const float*)d_in[10];
  const float* b2     = (const float*)d_in[12];
  const float* ln1w   = (const float*)d_in[13];
  const float* ln1b   = (const float*)d_in[14];
  const float* ln2w   = (const float*)d_in[15];
  const float* ln2b   = (const float*)d_in[16];
  const float* lnfw   = (const float*)d_in[17];
  const float* lnfb   = (const float*)d_in[18];
  const float* blm    = (const float*)d_in[20];
  float* out = (float*)d_out;

  char* ws = (char*)d_ws;
  u16*   X   = (u16*)(ws);                 //  8 MiB bf16 residual
  u16*   QKV = (u16*)(ws + ( 8u << 20));   // 24 MiB bf16 [NT][768]
  u16*   O   = (u16*)(ws + (32u << 20));   //  8 MiB bf16 attn out
  u16*   hB  = (u16*)(ws + (40u << 20));   //  8 MiB bf16 MLP hidden
  u16*   WT  = (u16*)(ws + (48u << 20));   // ~4.63 MiB bf16 weights
  float* nl  = (float*)(ws + (56u << 20)); // 64 KiB

  const size_t SM_QKV = (size_t)2*(128+128)*64*2;                    // 65536
  const size_t SM_AT  = (size_t)(64*268 + 32*264) * 2;               // 51200
  const size_t SM_F   = (size_t)(8192 + 32768 + 16896)*2 + 64*9*4*2; // 120320

  wconv_k<<<dim3(4, 4, 37), 256, 0, stream>>>(
      (const float*)d_in[4], (const float*)d_in[5], (const float*)d_in[6],
      (const float*)d_in[7], (const float*)d_in[9], (const float*)d_in[11],
      (const float*)d_in[19], WT);
  embed_k<<<NT / 4, 256, 0, stream>>>(idx, tok, pos, X);

  gemm3_k<128,128,512,2,4><<<dim3(128, 6), 512, SM_QKV, stream>>>(
      X, WT, QKV, 768);

  for (int l = 0; l < LAYERS; ++l){
    const u16* wo = WT + 1179648 + (size_t)(0*6 + l) * 65536;
    const u16* w1 = WT + 1179648 + (size_t)(1*6 + l) * 65536;
    const u16* w2 = WT + 1179648 + (size_t)(2*6 + l) * 65536;

    attn3_k<<<512, 256, SM_AT, stream>>>(QKV, O);

    gemmF_k<256,1,true,true,false,false><<<256, 1024, SM_F, stream>>>(
        O, wo, bo + l*256, X, ln1w + l*256, ln1b + l*256,
        w1, b1 + l*256, hB, 256, nullptr, nullptr);

    if (l < LAYERS - 1){
      gemmF_k<256,3,false,false,false,false><<<256, 1024, SM_F, stream>>>(
          hB, w2, b2 + l*256, X, ln2w + l*256, ln2b + l*256,
          WT + (size_t)(l+1) * 196608, nullptr, QKV, 768, nullptr, nullptr);
    } else {
      gemmF_k<128,1,false,true,true,true><<<256, 1024, SM_F, stream>>>(
          hB, w2, b2 + l*256, X, ln2w + l*256, ln2b + l*256,
          WT + 2359296, blm, out, 96, lnfw, lnfb);
    }
  }

  nll_k<<<NT / 4, 256, 0, stream>>>(out, target, nl);
  loss_k<<<1, 256, 0, stream>>>(nl, out + (size_t)NT * 96);
}